// Round 1
// baseline (1998.519 us; speedup 1.0000x reference)
//
#include <hip/hip_runtime.h>
#include <cstdint>

#define HH   512
#define HD2  1024
#define HD3  1536
#define EE   300
#define VV   32000
#define BB   32
#define LLn  64
#define TT   32

typedef unsigned short u16;
typedef __attribute__((ext_vector_type(8))) short short8;
typedef __attribute__((ext_vector_type(4))) float f32x4;

__device__ __forceinline__ float fast_tanh(float x) {
    float e = __expf(2.f * x);
    return 1.f - 2.f / (e + 1.f);
}
__device__ __forceinline__ float fast_sigmoid(float x) {
    float e = __expf(-x);
    return 1.f / (1.f + e);
}
__device__ __forceinline__ u16 f2bf(float x) {
    union { float f; unsigned u; } v; v.f = x;
    unsigned r = v.u + 0x7FFFu + ((v.u >> 16) & 1u);   // RNE
    return (u16)(r >> 16);
}

// ---------------------------------------------------------------------------
// Generic fp32 pre-GEMM: C[M x N] = A[M x K] @ W[K x N] + bias
// grid = (N/256, M/16), block = 256. Optional A-row gather (embedding lookup).
// ---------------------------------------------------------------------------
__global__ __launch_bounds__(256) void pre_gemm(
    const float* __restrict__ A, const float* __restrict__ W,
    const float* __restrict__ bias, float* __restrict__ C,
    int K, int N, const int* __restrict__ gather)
{
    __shared__ float a_lds[16 * 512];
    const int nt = blockIdx.x, mt = blockIdx.y, tid = threadIdx.x;
    const int col = nt * 256 + tid;

    float acc[16];
    const float bv = bias ? bias[col] : 0.f;
#pragma unroll
    for (int r = 0; r < 16; r++) acc[r] = bv;

    for (int kb = 0; kb < K; kb += 512) {
        const int klen = (K - kb < 512) ? (K - kb) : 512;
        const int row4 = klen >> 2;
        __syncthreads();
        for (int i = tid; i < 16 * row4; i += 256) {
            int r  = i / row4;
            int c4 = i - r * row4;
            int gr = mt * 16 + r;
            int src = gather ? gather[gr] : gr;
            float4 v = *(const float4*)(A + (size_t)src * K + kb + c4 * 4);
            *(float4*)(a_lds + r * klen + c4 * 4) = v;
        }
        __syncthreads();
        for (int k = 0; k < klen; k += 4) {
            const size_t wi = (size_t)(kb + k) * N + col;
            float w0 = W[wi];
            float w1 = W[wi + (size_t)N];
            float w2 = W[wi + (size_t)2 * N];
            float w3 = W[wi + (size_t)3 * N];
#pragma unroll
            for (int r = 0; r < 16; r++) {
                float4 a = *(const float4*)(a_lds + r * klen + k);
                acc[r] = fmaf(a.x, w0, acc[r]);
                acc[r] = fmaf(a.y, w1, acc[r]);
                acc[r] = fmaf(a.z, w2, acc[r]);
                acc[r] = fmaf(a.w, w3, acc[r]);
            }
        }
    }
#pragma unroll
    for (int r = 0; r < 16; r++)
        C[(size_t)(mt * 16 + r) * N + col] = acc[r];
}

// ---------------------------------------------------------------------------
// step_a: pure GEMM1 of step t: parts1[p] = s_t(k-chunk p) @ [W_a | W_hzr]
// grid = (6 col-tiles, 8 k-chunks of 64, 2 batch-halves), block = 256.
// ---------------------------------------------------------------------------
__global__ __launch_bounds__(256) void step_a(
    const float* __restrict__ s_buf, const float* __restrict__ W_a,
    const float* __restrict__ W_hzr, float* __restrict__ parts1)
{
    __shared__ float s_lds[64 * 16];   // [kk][b_local]
    const int jt = blockIdx.x, p = blockIdx.y, bh = blockIdx.z;
    const int tid = threadIdx.x;
    const int kk  = tid & 63, blq = tid >> 6;
    const int k0  = p * 64, b0 = bh * 16;

#pragma unroll
    for (int i = 0; i < 4; i++) {
        int bl = blq * 4 + i;
        s_lds[kk * 16 + bl] = s_buf[(b0 + bl) * HH + k0 + kk];
    }
    __syncthreads();

    const int j = jt * 256 + tid;
    const float* Wp; int ld;
    if (j < HH) { Wp = W_a + j;          ld = HH;  }
    else        { Wp = W_hzr + (j - HH); ld = HD2; }
    Wp += (size_t)k0 * ld;

    float acc[16];
#pragma unroll
    for (int r = 0; r < 16; r++) acc[r] = 0.f;
    for (int k = 0; k < 64; k++) {
        float w = Wp[(size_t)k * ld];
#pragma unroll
        for (int r = 0; r < 4; r++) {
            float4 s4 = *(const float4*)(s_lds + k * 16 + r * 4);
            acc[r * 4 + 0] = fmaf(s4.x, w, acc[r * 4 + 0]);
            acc[r * 4 + 1] = fmaf(s4.y, w, acc[r * 4 + 1]);
            acc[r * 4 + 2] = fmaf(s4.z, w, acc[r * 4 + 2]);
            acc[r * 4 + 3] = fmaf(s4.w, w, acc[r * 4 + 3]);
        }
    }
#pragma unroll
    for (int r = 0; r < 16; r++)
        parts1[((size_t)p * BB + b0 + r) * HD3 + j] = acc[r];
}

// ---------------------------------------------------------------------------
// step_b: fused attention + gates + (r*s)@W_hs + s-finalize + sseq write.
// grid = 32 (one block per batch row), block = 512 (8 waves).
// Thread tid owns h = tid throughout (gates in registers, no global bounce).
// ---------------------------------------------------------------------------
__global__ __launch_bounds__(512) void step_b(
    const float* __restrict__ parts1, const float* __restrict__ Uh,
    const float* __restrict__ Gc, const float* __restrict__ Ge,
    const float* __restrict__ W_hs,
    const float* __restrict__ b_a, const float* __restrict__ v_w,
    const float* __restrict__ v_b, const float* __restrict__ b_hzr,
    const float* __restrict__ b_hs,
    float* __restrict__ s_buf, u16* __restrict__ sseq, int t)
{
    const int b = blockIdx.x, tid = threadIdx.x;
    __shared__ float outs[HH];
    __shared__ float sc[512];
    __shared__ float attn_s[LLn];
    __shared__ float rs_s[HH];

    // outs[h] = b_a[h] + sum_p parts1[p][b][h]   (W_a block of GEMM1)
    {
        float a = b_a[tid];
#pragma unroll
        for (int p = 0; p < 8; p++)
            a += parts1[((size_t)p * BB + b) * HD3 + tid];
        outs[tid] = a;
    }
    __syncthreads();

    // scores: sc[jj*64+l] = partial dot over 64 h of tanh(outs+Uh) * v_w
    {
        const int l = tid & 63, jj = tid >> 6;
        const float* uh = Uh + ((size_t)b * LLn + l) * HH + jj * 64;
        const float* os = outs + jj * 64;
        const float* vw = v_w + jj * 64;
        float acc = 0.f;
#pragma unroll 8
        for (int h = 0; h < 64; h++)
            acc = fmaf(fast_tanh(os[h] + uh[h]), vw[h], acc);
        sc[tid] = acc;
    }
    __syncthreads();

    // softmax over L=64 (wave 0)
    if (tid < 64) {
        float v = v_b[0];
#pragma unroll
        for (int q = 0; q < 8; q++) v += sc[q * 64 + tid];
        float m = v;
        for (int o = 32; o > 0; o >>= 1) m = fmaxf(m, __shfl_xor(m, o));
        float e = __expf(v - m);
        float s = e;
        for (int o = 32; o > 0; o >>= 1) s += __shfl_xor(s, o);
        attn_s[tid] = e / s;
    }
    __syncthreads();

    // ctx gates: thread tid accumulates gates z/r/s at column h = tid.
    float g0 = 0.f, g1 = 0.f, g2 = 0.f;
    {
        const float* gc = Gc + (size_t)b * LLn * HD3 + tid;
#pragma unroll 4
        for (int l = 0; l < LLn; l++) {
            float a = attn_s[l];
            const float* gp = gc + (size_t)l * HD3;
            g0 = fmaf(a, gp[0],   g0);
            g1 = fmaf(a, gp[HH],  g1);
            g2 = fmaf(a, gp[HD2], g2);
        }
    }

    const float* ge = Ge + (size_t)(b * TT + t) * HD3;
    float gz = b_hzr[tid]      + ge[tid]       + g0;
    float gr = b_hzr[HH + tid] + ge[HH + tid]  + g1;
#pragma unroll
    for (int p = 0; p < 8; p++) {
        const float* pp = parts1 + ((size_t)p * BB + b) * HD3;
        gz += pp[HH + tid];
        gr += pp[HD2 + tid];
    }
    float z  = fast_sigmoid(gz);
    float r  = fast_sigmoid(gr);
    float sv = s_buf[b * HH + tid];
    rs_s[tid] = r * sv;
    float pst = ge[HD2 + tid] + g2 + b_hs[tid];
    __syncthreads();

    // gemm2: acc = sum_k rs_s[k] * W_hs[k][tid]  (W_hs L2-hot, coalesced)
    float a0 = 0.f, a1 = 0.f, a2 = 0.f, a3 = 0.f;
    {
        const float* wp = W_hs + tid;
#pragma unroll 4
        for (int k = 0; k < HH; k += 4) {
            a0 = fmaf(rs_s[k + 0], wp[(size_t)(k + 0) * HH], a0);
            a1 = fmaf(rs_s[k + 1], wp[(size_t)(k + 1) * HH], a1);
            a2 = fmaf(rs_s[k + 2], wp[(size_t)(k + 2) * HH], a2);
            a3 = fmaf(rs_s[k + 3], wp[(size_t)(k + 3) * HH], a3);
        }
    }
    float st = fast_tanh(pst + ((a0 + a1) + (a2 + a3)));
    float sn = fmaf(z, st - sv, sv);
    s_buf[b * HH + tid] = sn;
    sseq[((size_t)b * TT + t) * HH + tid] = f2bf(sn);
}

// ---------------------------------------------------------------------------
// final_gemm: out[1024 x 32000] = s_seq(bf16) @ W_out + b_out via
// mfma_f32_16x16x32_bf16. Block tile 256(M) x 64(N), K staged 32 at a time.
// grid = (500, 4), block = 256 (4 waves; wave w owns m-tiles 4w..4w+3).
// ---------------------------------------------------------------------------
__global__ __launch_bounds__(256) void final_gemm(
    const u16* __restrict__ Abf, const float* __restrict__ Wout,
    const float* __restrict__ b_out, float* __restrict__ out)
{
    __shared__ u16 a_lds[256 * 40];   // row stride 40 (pad)
    __shared__ u16 b_lds[64 * 40];    // [n][k], stride 40
    const int nb = blockIdx.x, mb = blockIdx.y, tid = threadIdx.x;
    const int w = tid >> 6, ln = tid & 63;
    const int quad = ln >> 4, lm = ln & 15;
    const int n0 = nb * 64;

    f32x4 acc[4][4];
#pragma unroll
    for (int r = 0; r < 4; r++)
#pragma unroll
        for (int c = 0; c < 4; c++)
            acc[r][c] = (f32x4){0.f, 0.f, 0.f, 0.f};

    for (int kt = 0; kt < 16; kt++) {
        const int k0 = kt * 32;
        {   // stage A: one row-chunk (32 bf16 = 64 B = 4 x uint4) per thread
            const uint4* src = (const uint4*)(Abf + ((size_t)(mb * 256 + tid)) * HH + k0);
            uint4 v0 = src[0], v1 = src[1], v2 = src[2], v3 = src[3];
            uint4* dst = (uint4*)(a_lds + tid * 40);
            dst[0] = v0; dst[1] = v1; dst[2] = v2; dst[3] = v3;
        }
        {   // stage B: fp32 load (coalesced over n), convert, transpose into LDS
            int kr = tid >> 3, c8 = (tid & 7) * 8;
            const float4* wp = (const float4*)(Wout + (size_t)(k0 + kr) * VV + n0 + c8);
            float4 f0 = wp[0], f1 = wp[1];
            u16 u[8] = { f2bf(f0.x), f2bf(f0.y), f2bf(f0.z), f2bf(f0.w),
                         f2bf(f1.x), f2bf(f1.y), f2bf(f1.z), f2bf(f1.w) };
#pragma unroll
            for (int j = 0; j < 8; j++)
                b_lds[(c8 + j) * 40 + kr] = u[j];
        }
        __syncthreads();
        short8 af[4], bfr[4];
#pragma unroll
        for (int r = 0; r < 4; r++)
            af[r] = *(const short8*)(a_lds + ((w * 4 + r) * 16 + lm) * 40 + quad * 8);
#pragma unroll
        for (int c = 0; c < 4; c++)
            bfr[c] = *(const short8*)(b_lds + (c * 16 + lm) * 40 + quad * 8);
#pragma unroll
        for (int r = 0; r < 4; r++)
#pragma unroll
            for (int c = 0; c < 4; c++)
                acc[r][c] = __builtin_amdgcn_mfma_f32_16x16x32_bf16(
                    af[r], bfr[c], acc[r][c], 0, 0, 0);
        __syncthreads();
    }
#pragma unroll
    for (int r = 0; r < 4; r++) {
        int row = mb * 256 + (w * 4 + r) * 16 + quad * 4;
#pragma unroll
        for (int c = 0; c < 4; c++) {
            int col = n0 + c * 16 + lm;
            float bo = b_out[col];
#pragma unroll
            for (int q = 0; q < 4; q++)
                out[(size_t)(row + q) * VV + col] = acc[r][c][q] + bo;
        }
    }
}

// ---------------------------------------------------------------------------
extern "C" void kernel_launch(void* const* d_in, const int* in_sizes, int n_in,
                              void* d_out, int out_size, void* d_ws, size_t ws_size,
                              hipStream_t stream)
{
    const float* enc_h  = (const float*)d_in[0];
    const float* prev_s = (const float*)d_in[1];
    const int*   tw     = (const int*)  d_in[2];
    const float* embed  = (const float*)d_in[3];
    const float* W_a    = (const float*)d_in[4];
    const float* b_a    = (const float*)d_in[5];
    const float* U_a    = (const float*)d_in[6];
    const float* b_Ua   = (const float*)d_in[7];
    const float* v_w    = (const float*)d_in[8];
    const float* v_b    = (const float*)d_in[9];
    const float* W_emb  = (const float*)d_in[10];
    const float* b_emb  = (const float*)d_in[11];
    const float* W_hzr  = (const float*)d_in[12];
    const float* b_hzr  = (const float*)d_in[13];
    const float* W_hs   = (const float*)d_in[14];
    const float* b_hs   = (const float*)d_in[15];
    const float* W_ctx  = (const float*)d_in[16];
    const float* b_ctx  = (const float*)d_in[17];
    const float* W_out  = (const float*)d_in[18];
    const float* b_out  = (const float*)d_in[19];
    float* out = (float*)d_out;

    float* ws = (float*)d_ws;
    float* Uh     = ws;  ws += 2048 * 512;     // enc_h @ U_a + b_Ua
    float* Gc     = ws;  ws += 2048 * 1536;    // enc_h @ W_ctx + b_ctx
    float* Ge     = ws;  ws += 1024 * 1536;    // embed[tw] @ W_emb + b_emb
    float* parts1 = ws;  ws += 8 * 32 * 1536;  // k-chunk partials of s@[W_a|W_hzr]
    float* s_buf  = ws;  ws += 32 * 512;       // current hidden state s_t
    u16*   sseq   = (u16*)ws;                  // 1024 x 512 bf16

    // s_0 = prev_s
    hipMemcpyAsync(s_buf, prev_s, (size_t)BB * HH * sizeof(float),
                   hipMemcpyDeviceToDevice, stream);

    // Loop-invariant precomputes
    pre_gemm<<<dim3(2, 128), 256, 0, stream>>>(enc_h, U_a,   b_Ua,  Uh, 1024, 512,  nullptr);
    pre_gemm<<<dim3(6, 128), 256, 0, stream>>>(enc_h, W_ctx, b_ctx, Gc, 1024, 1536, nullptr);
    pre_gemm<<<dim3(6, 64),  256, 0, stream>>>(embed, W_emb, b_emb, Ge, 300,  1536, tw);

    for (int t = 0; t < TT; t++) {
        step_a<<<dim3(6, 8, 2), 256, 0, stream>>>(s_buf, W_a, W_hzr, parts1);
        step_b<<<dim3(32), 512, 0, stream>>>(parts1, Uh, Gc, Ge, W_hs,
                                             b_a, v_w, v_b, b_hzr, b_hs,
                                             s_buf, sseq, t);
    }
    final_gemm<<<dim3(500, 4), 256, 0, stream>>>(sseq, W_out, b_out, out);
}

// Round 2
// 1599.649 us; speedup vs baseline: 1.2493x; 1.2493x over previous
//
#include <hip/hip_runtime.h>
#include <cstdint>

#define HH   512
#define HD2  1024
#define HD3  1536
#define EE   300
#define VV   32000
#define BB   32
#define LLn  64
#define TT   32

typedef unsigned short u16;
typedef __attribute__((ext_vector_type(8))) short short8;
typedef __attribute__((ext_vector_type(4))) float f32x4;

__device__ __forceinline__ float fast_tanh(float x) {
    float e = __expf(2.f * x);
    return 1.f - 2.f / (e + 1.f);
}
__device__ __forceinline__ float fast_sigmoid(float x) {
    float e = __expf(-x);
    return 1.f / (1.f + e);
}
__device__ __forceinline__ u16 f2bf(float x) {
    union { float f; unsigned u; } v; v.f = x;
    unsigned r = v.u + 0x7FFFu + ((v.u >> 16) & 1u);   // RNE
    return (u16)(r >> 16);
}

// ---------------------------------------------------------------------------
// conv_hilo: fp32 -> (bf16 hi, bf16 lo) truncation split, with optional row
// gather and zero padding (rows >= rows_valid or cols >= cols_valid -> 0).
// hi + lo recovers ~16 mantissa bits: hi*h + hi*l + lo*h GEMM ~ fp32 exact.
// ---------------------------------------------------------------------------
__global__ __launch_bounds__(256) void conv_hilo(
    const float* __restrict__ src, const int* __restrict__ gather,
    int rows_out, int cols_out, int rows_valid, int cols_valid,
    u16* __restrict__ hi, u16* __restrict__ lo)
{
    int idx = blockIdx.x * 256 + threadIdx.x;
    if (idx >= rows_out * cols_out) return;
    int r = idx / cols_out, c = idx - r * cols_out;
    float x = 0.f;
    if (r < rows_valid && c < cols_valid) {
        int sr = gather ? gather[r] : r;
        x = src[(size_t)sr * cols_valid + c];
    }
    union { float f; unsigned u; } v; v.f = x;
    unsigned uh = v.u & 0xFFFF0000u;
    float res = x - __uint_as_float(uh);   // exact (low mantissa bits)
    union { float f; unsigned u; } w; w.f = res;
    hi[idx] = (u16)(v.u >> 16);
    lo[idx] = (u16)(w.u >> 16);
}

// ---------------------------------------------------------------------------
// pre_mfma: C[M x N] fp32 = A @ W + bias via bf16 hi/lo x3 MFMA
// (A_hi*W_hi + A_hi*W_lo + A_lo*W_hi). Tile 256(M) x 64(N), K staged 32.
// grid = (N/64, M/256), block = 256 (4 waves). K = KSTEPS*32 (zero-padded).
// ---------------------------------------------------------------------------
template<int KSTEPS>
__global__ __launch_bounds__(256) void pre_mfma(
    const u16* __restrict__ Ahi, const u16* __restrict__ Alo,
    const u16* __restrict__ Whi, const u16* __restrict__ Wlo,
    const float* __restrict__ bias, float* __restrict__ C, int N)
{
    __shared__ u16 ah[256 * 40], al[256 * 40];   // [m][k], stride 40
    __shared__ u16 bh[64 * 40],  bl[64 * 40];    // [n][k], stride 40
    const int nb = blockIdx.x, mb = blockIdx.y, tid = threadIdx.x;
    const int w = tid >> 6, ln = tid & 63;
    const int quad = ln >> 4, lm = ln & 15;
    const int n0 = nb * 64;
    const int K = KSTEPS * 32;

    f32x4 acc[4][4];
#pragma unroll
    for (int r = 0; r < 4; r++)
#pragma unroll
        for (int c = 0; c < 4; c++)
            acc[r][c] = (f32x4){0.f, 0.f, 0.f, 0.f};

    for (int kt = 0; kt < KSTEPS; kt++) {
        const int k0 = kt * 32;
        {   // stage A: thread tid owns row tid (32 bf16 hi + 32 lo = 2x64 B)
            const uint4* sh = (const uint4*)(Ahi + (size_t)(mb * 256 + tid) * K + k0);
            const uint4* sl = (const uint4*)(Alo + (size_t)(mb * 256 + tid) * K + k0);
            uint4 h0 = sh[0], h1 = sh[1], h2 = sh[2], h3 = sh[3];
            uint4 l0 = sl[0], l1 = sl[1], l2 = sl[2], l3 = sl[3];
            uint4* dh = (uint4*)(ah + tid * 40);
            dh[0] = h0; dh[1] = h1; dh[2] = h2; dh[3] = h3;
            uint4* dl = (uint4*)(al + tid * 40);
            dl[0] = l0; dl[1] = l1; dl[2] = l2; dl[3] = l3;
        }
        {   // stage W: row kr = tid>>3, 8 cols at c8; transpose into [n][k]
            const int kr = tid >> 3, c8 = (tid & 7) * 8;
            union { uint4 v; u16 u[8]; } uh, ul;
            uh.v = *(const uint4*)(Whi + (size_t)(k0 + kr) * N + n0 + c8);
            ul.v = *(const uint4*)(Wlo + (size_t)(k0 + kr) * N + n0 + c8);
#pragma unroll
            for (int j = 0; j < 8; j++) {
                bh[(c8 + j) * 40 + kr] = uh.u[j];
                bl[(c8 + j) * 40 + kr] = ul.u[j];
            }
        }
        __syncthreads();
        short8 afh[4], afl[4], bfh[4], bfl[4];
#pragma unroll
        for (int r = 0; r < 4; r++) {
            afh[r] = *(const short8*)(ah + ((w * 4 + r) * 16 + lm) * 40 + quad * 8);
            afl[r] = *(const short8*)(al + ((w * 4 + r) * 16 + lm) * 40 + quad * 8);
        }
#pragma unroll
        for (int c = 0; c < 4; c++) {
            bfh[c] = *(const short8*)(bh + (c * 16 + lm) * 40 + quad * 8);
            bfl[c] = *(const short8*)(bl + (c * 16 + lm) * 40 + quad * 8);
        }
#pragma unroll
        for (int r = 0; r < 4; r++)
#pragma unroll
            for (int c = 0; c < 4; c++) {
                acc[r][c] = __builtin_amdgcn_mfma_f32_16x16x32_bf16(
                    afh[r], bfh[c], acc[r][c], 0, 0, 0);
                acc[r][c] = __builtin_amdgcn_mfma_f32_16x16x32_bf16(
                    afh[r], bfl[c], acc[r][c], 0, 0, 0);
                acc[r][c] = __builtin_amdgcn_mfma_f32_16x16x32_bf16(
                    afl[r], bfh[c], acc[r][c], 0, 0, 0);
            }
        __syncthreads();
    }
#pragma unroll
    for (int r = 0; r < 4; r++) {
        int row = mb * 256 + (w * 4 + r) * 16 + quad * 4;
#pragma unroll
        for (int c = 0; c < 4; c++) {
            int col = n0 + c * 16 + lm;
            float bo = bias[col];
#pragma unroll
            for (int q2 = 0; q2 < 4; q2++)
                C[(size_t)(row + q2) * N + col] = acc[r][c][q2] + bo;
        }
    }
}

// ---------------------------------------------------------------------------
// step_a: GEMM1 of step t: parts1[p] = s_t(k-chunk p) @ [W_a | W_hzr]
// grid = (6 col-tiles, 8 k-chunks of 64, 4 batch-eighths), block = 256.
// ---------------------------------------------------------------------------
__global__ __launch_bounds__(256) void step_a(
    const float* __restrict__ s_buf, const float* __restrict__ W_a,
    const float* __restrict__ W_hzr, float* __restrict__ parts1)
{
    __shared__ float s_lds[64 * 8];   // [kk][b_local]
    const int jt = blockIdx.x, p = blockIdx.y, bq = blockIdx.z;
    const int tid = threadIdx.x;
    const int kk  = tid & 63, blq = tid >> 6;
    const int k0  = p * 64, b0 = bq * 8;

#pragma unroll
    for (int i = 0; i < 2; i++) {
        int bl = blq * 2 + i;
        s_lds[kk * 8 + bl] = s_buf[(b0 + bl) * HH + k0 + kk];
    }
    __syncthreads();

    const int j = jt * 256 + tid;
    const float* Wp; int ld;
    if (j < HH) { Wp = W_a + j;          ld = HH;  }
    else        { Wp = W_hzr + (j - HH); ld = HD2; }
    Wp += (size_t)k0 * ld;

    float acc[8];
#pragma unroll
    for (int r = 0; r < 8; r++) acc[r] = 0.f;
    for (int k = 0; k < 64; k++) {
        float w = Wp[(size_t)k * ld];
#pragma unroll
        for (int r = 0; r < 2; r++) {
            float4 s4 = *(const float4*)(s_lds + k * 8 + r * 4);
            acc[r * 4 + 0] = fmaf(s4.x, w, acc[r * 4 + 0]);
            acc[r * 4 + 1] = fmaf(s4.y, w, acc[r * 4 + 1]);
            acc[r * 4 + 2] = fmaf(s4.z, w, acc[r * 4 + 2]);
            acc[r * 4 + 3] = fmaf(s4.w, w, acc[r * 4 + 3]);
        }
    }
#pragma unroll
    for (int r = 0; r < 8; r++)
        parts1[((size_t)p * BB + b0 + r) * HD3 + j] = acc[r];
}

// ---------------------------------------------------------------------------
// step_b: fused attention + gates + (r*s)@W_hs + s-finalize + sseq write.
// grid = (32 batch, 4 h-quarters), block = 256. Each block redundantly
// computes scores/softmax/r*s (cheap) but owns only 128 h-columns of
// z/pst/gemm2/finalize -> 4x CUs, ~1/3 the L2 traffic of the monolith.
// Double-buffered s (s_prev -> s_next) to avoid cross-block races.
// ---------------------------------------------------------------------------
__global__ __launch_bounds__(256) void step_b(
    const float* __restrict__ parts1, const float* __restrict__ Uh,
    const float* __restrict__ Gc, const float* __restrict__ Ge,
    const float* __restrict__ W_hs,
    const float* __restrict__ b_a, const float* __restrict__ v_w,
    const float* __restrict__ v_b, const float* __restrict__ b_hzr,
    const float* __restrict__ b_hs,
    const float* __restrict__ s_prev, float* __restrict__ s_next,
    u16* __restrict__ sseq, int t)
{
    const int b = blockIdx.x, q = blockIdx.y, tid = threadIdx.x;
    __shared__ float outs[HH];
    __shared__ float red[256];
    __shared__ float attn_s[LLn];
    __shared__ float rs_s[HH];
    __shared__ float zb_s[128], pst_s[128];

    // outs[h] = b_a[h] + sum_p parts1[p][b][h]
    for (int h = tid; h < HH; h += 256) {
        float a = b_a[h];
#pragma unroll
        for (int p = 0; p < 8; p++)
            a += parts1[((size_t)p * BB + b) * HD3 + h];
        outs[h] = a;
    }
    __syncthreads();

    // scores: (l = tid&63, jj = tid>>6) partial dot over 128 h
    {
        const int l = tid & 63, jj = tid >> 6;
        const float* uh = Uh + ((size_t)b * LLn + l) * HH + jj * 128;
        const float* os = outs + jj * 128;
        const float* vw = v_w + jj * 128;
        float acc = 0.f;
#pragma unroll 8
        for (int i = 0; i < 128; i++)
            acc = fmaf(fast_tanh(os[i] + uh[i]), vw[i], acc);
        red[tid] = acc;
    }
    __syncthreads();

    // softmax over L=64 (wave 0)
    if (tid < 64) {
        float v = red[tid] + red[64 + tid] + red[128 + tid] + red[192 + tid] + v_b[0];
        float m = v;
        for (int o = 32; o > 0; o >>= 1) m = fmaxf(m, __shfl_xor(m, o));
        float e = __expf(v - m);
        float s = e;
        for (int o = 32; o > 0; o >>= 1) s += __shfl_xor(s, o);
        attn_s[tid] = e / s;
    }
    __syncthreads();

    const float* ge = Ge + (size_t)(b * TT + t) * HD3;

    // r-gate + rs for ALL 512 h (2 per thread) — redundant across q, needed
    // as gemm2 input.
    {
        float g1a = 0.f, g1b = 0.f;
        const float* gc = Gc + (size_t)b * LLn * HD3 + HH;
#pragma unroll 4
        for (int l = 0; l < LLn; l++) {
            float a = attn_s[l];
            g1a = fmaf(a, gc[(size_t)l * HD3 + tid],       g1a);
            g1b = fmaf(a, gc[(size_t)l * HD3 + tid + 256], g1b);
        }
        float gra = b_hzr[HH + tid]       + ge[HH + tid]       + g1a;
        float grb = b_hzr[HH + tid + 256] + ge[HH + tid + 256] + g1b;
#pragma unroll
        for (int p = 0; p < 8; p++) {
            const float* pp = parts1 + ((size_t)p * BB + b) * HD3;
            gra += pp[HD2 + tid];
            grb += pp[HD2 + tid + 256];
        }
        rs_s[tid]       = fast_sigmoid(gra) * s_prev[b * HH + tid];
        rs_s[tid + 256] = fast_sigmoid(grb) * s_prev[b * HH + tid + 256];
    }

    // z (waves 0-1) / pst (waves 2-3) for own 128 h
    {
        const int hq = q * 128 + (tid & 127);
        if (tid < 128) {
            float g0 = 0.f;
            const float* gc = Gc + (size_t)b * LLn * HD3;
#pragma unroll 4
            for (int l = 0; l < LLn; l++)
                g0 = fmaf(attn_s[l], gc[(size_t)l * HD3 + hq], g0);
            float gz = b_hzr[hq] + ge[hq] + g0;
#pragma unroll
            for (int p = 0; p < 8; p++)
                gz += parts1[((size_t)p * BB + b) * HD3 + HH + hq];
            zb_s[tid] = fast_sigmoid(gz);
        } else {
            float g2 = 0.f;
            const float* gc = Gc + (size_t)b * LLn * HD3 + HD2;
#pragma unroll 4
            for (int l = 0; l < LLn; l++)
                g2 = fmaf(attn_s[l], gc[(size_t)l * HD3 + hq], g2);
            pst_s[tid - 128] = ge[HD2 + hq] + g2 + b_hs[hq];
        }
    }
    __syncthreads();

    // gemm2 slice: col c = q*128 + (tid&127), k-half = tid>>7 (256 k each)
    {
        const int c = tid & 127, half = tid >> 7;
        const int h0 = q * 128 + c;
        const float* wp = W_hs + (size_t)(half * 256) * HH + h0;
        const float* rp = rs_s + half * 256;
        float a0 = 0.f, a1 = 0.f, a2 = 0.f, a3 = 0.f;
#pragma unroll 4
        for (int k = 0; k < 256; k += 4) {
            a0 = fmaf(rp[k + 0], wp[(size_t)(k + 0) * HH], a0);
            a1 = fmaf(rp[k + 1], wp[(size_t)(k + 1) * HH], a1);
            a2 = fmaf(rp[k + 2], wp[(size_t)(k + 2) * HH], a2);
            a3 = fmaf(rp[k + 3], wp[(size_t)(k + 3) * HH], a3);
        }
        red[tid] = (a0 + a1) + (a2 + a3);
    }
    __syncthreads();

    if (tid < 128) {
        const int h0 = q * 128 + tid;
        float tot = red[tid] + red[128 + tid];
        float st  = fast_tanh(pst_s[tid] + tot);
        float sv  = s_prev[b * HH + h0];
        float sn  = fmaf(zb_s[tid], st - sv, sv);
        s_next[b * HH + h0] = sn;
        sseq[((size_t)b * TT + t) * HH + h0] = f2bf(sn);
    }
}

// ---------------------------------------------------------------------------
// final_gemm: out[1024 x 32000] = s_seq(bf16) @ W_out + b_out via
// mfma_f32_16x16x32_bf16. Block tile 256(M) x 64(N), K staged 32 at a time.
// grid = (500, 4), block = 256 (4 waves; wave w owns m-tiles 4w..4w+3).
// ---------------------------------------------------------------------------
__global__ __launch_bounds__(256) void final_gemm(
    const u16* __restrict__ Abf, const float* __restrict__ Wout,
    const float* __restrict__ b_out, float* __restrict__ out)
{
    __shared__ u16 a_lds[256 * 40];   // row stride 40 (pad)
    __shared__ u16 b_lds[64 * 40];    // [n][k], stride 40
    const int nb = blockIdx.x, mb = blockIdx.y, tid = threadIdx.x;
    const int w = tid >> 6, ln = tid & 63;
    const int quad = ln >> 4, lm = ln & 15;
    const int n0 = nb * 64;

    f32x4 acc[4][4];
#pragma unroll
    for (int r = 0; r < 4; r++)
#pragma unroll
        for (int c = 0; c < 4; c++)
            acc[r][c] = (f32x4){0.f, 0.f, 0.f, 0.f};

    for (int kt = 0; kt < 16; kt++) {
        const int k0 = kt * 32;
        {   // stage A: one row-chunk (32 bf16 = 64 B = 4 x uint4) per thread
            const uint4* src = (const uint4*)(Abf + ((size_t)(mb * 256 + tid)) * HH + k0);
            uint4 v0 = src[0], v1 = src[1], v2 = src[2], v3 = src[3];
            uint4* dst = (uint4*)(a_lds + tid * 40);
            dst[0] = v0; dst[1] = v1; dst[2] = v2; dst[3] = v3;
        }
        {   // stage B: fp32 load (coalesced over n), convert, transpose into LDS
            int kr = tid >> 3, c8 = (tid & 7) * 8;
            const float4* wp = (const float4*)(Wout + (size_t)(k0 + kr) * VV + n0 + c8);
            float4 f0 = wp[0], f1 = wp[1];
            u16 u[8] = { f2bf(f0.x), f2bf(f0.y), f2bf(f0.z), f2bf(f0.w),
                         f2bf(f1.x), f2bf(f1.y), f2bf(f1.z), f2bf(f1.w) };
#pragma unroll
            for (int j = 0; j < 8; j++)
                b_lds[(c8 + j) * 40 + kr] = u[j];
        }
        __syncthreads();
        short8 af[4], bfr[4];
#pragma unroll
        for (int r = 0; r < 4; r++)
            af[r] = *(const short8*)(a_lds + ((w * 4 + r) * 16 + lm) * 40 + quad * 8);
#pragma unroll
        for (int c = 0; c < 4; c++)
            bfr[c] = *(const short8*)(b_lds + (c * 16 + lm) * 40 + quad * 8);
#pragma unroll
        for (int r = 0; r < 4; r++)
#pragma unroll
            for (int c = 0; c < 4; c++)
                acc[r][c] = __builtin_amdgcn_mfma_f32_16x16x32_bf16(
                    af[r], bfr[c], acc[r][c], 0, 0, 0);
        __syncthreads();
    }
#pragma unroll
    for (int r = 0; r < 4; r++) {
        int row = mb * 256 + (w * 4 + r) * 16 + quad * 4;
#pragma unroll
        for (int c = 0; c < 4; c++) {
            int col = n0 + c * 16 + lm;
            float bo = b_out[col];
#pragma unroll
            for (int q = 0; q < 4; q++)
                out[(size_t)(row + q) * VV + col] = acc[r][c][q] + bo;
        }
    }
}

// ---------------------------------------------------------------------------
extern "C" void kernel_launch(void* const* d_in, const int* in_sizes, int n_in,
                              void* d_out, int out_size, void* d_ws, size_t ws_size,
                              hipStream_t stream)
{
    const float* enc_h  = (const float*)d_in[0];
    const float* prev_s = (const float*)d_in[1];
    const int*   tw     = (const int*)  d_in[2];
    const float* embed  = (const float*)d_in[3];
    const float* W_a    = (const float*)d_in[4];
    const float* b_a    = (const float*)d_in[5];
    const float* U_a    = (const float*)d_in[6];
    const float* b_Ua   = (const float*)d_in[7];
    const float* v_w    = (const float*)d_in[8];
    const float* v_b    = (const float*)d_in[9];
    const float* W_emb  = (const float*)d_in[10];
    const float* b_emb  = (const float*)d_in[11];
    const float* W_hzr  = (const float*)d_in[12];
    const float* b_hzr  = (const float*)d_in[13];
    const float* W_hs   = (const float*)d_in[14];
    const float* b_hs   = (const float*)d_in[15];
    const float* W_ctx  = (const float*)d_in[16];
    const float* b_ctx  = (const float*)d_in[17];
    const float* W_out  = (const float*)d_in[18];
    const float* b_out  = (const float*)d_in[19];
    float* out = (float*)d_out;

    float* ws = (float*)d_ws;
    float* Uh     = ws;  ws += 2048 * 512;     // enc_h @ U_a + b_Ua
    float* Gc     = ws;  ws += 2048 * 1536;    // enc_h @ W_ctx + b_ctx
    float* Ge     = ws;  ws += 1024 * 1536;    // embed[tw] @ W_emb + b_emb
    float* parts1 = ws;  ws += 8 * 32 * 1536;  // k-chunk partials of s@[W_a|W_hzr]
    float* s0     = ws;  ws += 32 * 512;
    float* s1     = ws;  ws += 32 * 512;
    u16* sseq = (u16*)ws;  ws += (1024 * 512) / 2;     // bf16
    u16* EHhi = (u16*)ws;  ws += (2048 * 1024) / 2;
    u16* EHlo = (u16*)ws;  ws += (2048 * 1024) / 2;
    u16* UAhi = (u16*)ws;  ws += (1024 * 512) / 2;
    u16* UAlo = (u16*)ws;  ws += (1024 * 512) / 2;
    u16* WChi = (u16*)ws;  ws += (1024 * 1536) / 2;
    u16* WClo = (u16*)ws;  ws += (1024 * 1536) / 2;
    u16* WEhi = (u16*)ws;  ws += (320 * 1536) / 2;
    u16* WElo = (u16*)ws;  ws += (320 * 1536) / 2;
    u16* AGhi = (u16*)ws;  ws += (1024 * 320) / 2;
    u16* AGlo = (u16*)ws;  ws += (1024 * 320) / 2;

    // s_0 = prev_s
    hipMemcpyAsync(s0, prev_s, (size_t)BB * HH * sizeof(float),
                   hipMemcpyDeviceToDevice, stream);

    // hi/lo conversions (truncation split)
    conv_hilo<<<dim3(8192), 256, 0, stream>>>(enc_h, nullptr, 2048, 1024, 2048, 1024, EHhi, EHlo);
    conv_hilo<<<dim3(2048), 256, 0, stream>>>(U_a,   nullptr, 1024, 512,  1024, 512,  UAhi, UAlo);
    conv_hilo<<<dim3(6144), 256, 0, stream>>>(W_ctx, nullptr, 1024, 1536, 1024, 1536, WChi, WClo);
    conv_hilo<<<dim3(1920), 256, 0, stream>>>(W_emb, nullptr, 320,  1536, 300,  1536, WEhi, WElo);
    conv_hilo<<<dim3(1280), 256, 0, stream>>>(embed, tw,      1024, 320,  1024, 300,  AGhi, AGlo);

    // Loop-invariant precomputes via bf16x3 MFMA
    pre_mfma<32><<<dim3(8, 8),  256, 0, stream>>>(EHhi, EHlo, UAhi, UAlo, b_Ua,  Uh, 512);
    pre_mfma<32><<<dim3(24, 8), 256, 0, stream>>>(EHhi, EHlo, WChi, WClo, b_ctx, Gc, 1536);
    pre_mfma<10><<<dim3(24, 4), 256, 0, stream>>>(AGhi, AGlo, WEhi, WElo, b_emb, Ge, 1536);

    for (int t = 0; t < TT; t++) {
        float* sA = (t & 1) ? s1 : s0;
        float* sB = (t & 1) ? s0 : s1;
        step_a<<<dim3(6, 8, 4), 256, 0, stream>>>(sA, W_a, W_hzr, parts1);
        step_b<<<dim3(32, 4), 256, 0, stream>>>(parts1, Uh, Gc, Ge, W_hs,
                                                b_a, v_w, v_b, b_hzr, b_hs,
                                                sA, sB, sseq, t);
    }
    final_gemm<<<dim3(500, 4), 256, 0, stream>>>(sseq, W_out, b_out, out);
}